// Round 2
// baseline (242.268 us; speedup 1.0000x reference)
//
#include <hip/hip_runtime.h>
#include <hip/hip_bf16.h>
#include <stdint.h>

// Problem constants (fixed by setup_inputs)
#define FCB 2            // codebooks
#define BB 16            // batch
#define NN 256           // tokens per (b)
#define EDIM 1024
#define CC 512           // channels per codebook
#define NE 4096          // prototypes per codebook
#define TOKENS (BB*FCB*NN)   // 8192
#define ROWS (FCB*NE)        // 8192 emb rows
#define OUT_LOSS (BB*NN*EDIM)   // 4194304 (also the element count for the mean)
#define OUT_IDX  (OUT_LOSS + 1)
#define MARGIN 0.15f     // rescore margin, v-units (v = z.e/||e|| ~ 22.6*cos); ~24 sigma of bf16 noise

typedef __attribute__((ext_vector_type(8))) short bf16x8;   // MFMA A/B frag (4 VGPRs)
typedef __attribute__((ext_vector_type(4))) float f32x4;    // 16x16 MFMA C/D frag

// monotonic float<->uint mapping for packed argmax
__device__ __forceinline__ unsigned int ford(float v) {
    unsigned int u = __float_as_uint(v);
    return (u & 0x80000000u) ? ~u : (u | 0x80000000u);
}
__device__ __forceinline__ float unford(unsigned int u) {
    unsigned int b = (u & 0x80000000u) ? (u & 0x7fffffffu) : ~u;
    return __uint_as_float(b);
}

// ---------------------------------------------------------------------------
// ws layout:
//   [0]        norm_sq   8192 f32                   (32 KB)  memset 0, atomic-accumulated
//   [32768]    cand      8192 tok x 64 slots x 2 u32 (4 MB)  top-2 per 64-col group
//   [32768+4M] (hole, 32 KB — was loss_tok, now fused into rescore)
//   [+32KB]    z_hi      2*4096*512 bf16            (8 MB)   fragment-packed
//   [+8MB]     e_hi      2*4096*512 bf16            (8 MB)
// Packed layout: elem = ((f*256 + R)*64 + Q)*128 + m*8 + j
//   (R = 16-row tile, Q = 8-elem k-chunk, m = row-in-tile, j = elem).
//   One 1-KB staging chunk = (R, qb..qb+3) = 16 rows x 32 k; both the
//   global_load_lds staging and ds_read_b128 fragment reads are lane-linear
//   (lane <-> 16 B), conflict-free.  (R3/R5-proven layout.)
// ---------------------------------------------------------------------------

// ---- pack: fp32 -> bf16 hi, fragment-packed; emb blocks also accumulate ----
// per-row norm^2 partials into norm_sq (selection-only precision).
__global__ __launch_bounds__(256) void pack_hi(
    const float* __restrict__ z, const float* __restrict__ emb,
    short* __restrict__ z_hi, short* __restrict__ e_hi,
    float* __restrict__ norm_sq)
{
    __shared__ float red[256];
    int bid = blockIdx.x;
    int tid = threadIdx.x;
    bool is_emb = (bid >= 2048);
    const float* src; short* hi; int RS, FRO, FCO;
    if (!is_emb) { src = z;   hi = z_hi; RS = EDIM; FRO = 0;  FCO = CC; }
    else         { src = emb; hi = e_hi; RS = CC;   FRO = NE; FCO = 0; bid -= 2048; }
    int u = bid * 256 + tid;                  // [0, 524288)
    int m = u & 15;
    int Q = (u >> 4) & 63;
    int R = (u >> 10) & 255;
    int f = u >> 18;
    int row = R * 16 + m;
    const float* s = src + (size_t)(f * FRO + row) * RS + f * FCO + Q * 8;
    float4 v0 = *(const float4*)s;
    float4 v1 = *(const float4*)(s + 4);
    float vv[8] = {v0.x, v0.y, v0.z, v0.w, v1.x, v1.y, v1.z, v1.w};
    bf16x8 h8;
    float ss = 0.f;
    #pragma unroll
    for (int j = 0; j < 8; ++j) {
        __hip_bfloat16 hb = __float2bfloat16(vv[j]);
        h8[j] = *(short*)&hb;
        ss = fmaf(vv[j], vv[j], ss);
    }
    *(bf16x8*)(hi + (size_t)u * 8) = h8;

    if (is_emb) {
        // block covers 16 rows x 128 k-elems; reduce over the 16 Q-threads/row
        red[tid] = ss;
        __syncthreads();
        if (tid < 16) {
            float t = 0.f;
            #pragma unroll
            for (int q = 0; q < 16; ++q) t += red[tid + 16 * q];
            int bf = (bid * 256) >> 18;
            int bR = ((bid * 256) >> 10) & 255;
            atomicAdd(norm_sq + bf * NE + bR * 16 + tid, t);
        }
    }
}

// ---------------------------------------------------------------------------
// 256x128 bf16 MFMA GEMM (BK=64) + per-token top-2-per-64col select.
// 8 waves (4M x 2N), wave = 64x64 = 4x4 tiles of 16x16x32, acc[4][4].
// LDS 48 KiB, single logical buffer split by k-half:
//   [kh0: A 16K | B 8K][kh1: A 16K | B 8K]
// Phase (one k-half h of step t):
//   { 8x ds_read frags(kh_h(t)); __syncthreads(); stage kh_h(t+1) in place;
//     16 MFMA }
// The syncthreads' vmcnt(0)+lgkmcnt(0) drain only ever waits on stages issued
// a FULL phase earlier (the just-issued stage sits after the barrier), so HBM/
// L2 latency is covered by ~1000 cyc of MFMA+reads; the barrier also proves
// all waves finished reading the region before it is overwritten (in-place
// double-buffer by k-half, race-free by construction). 48 KiB LDS + ~121
// unified regs -> 2 blocks/CU (16 waves) for cross-block overlap on top.
// ---------------------------------------------------------------------------
__global__ __launch_bounds__(512, 4) void gemm_sel(
    const short* __restrict__ zh, const short* __restrict__ eh,
    const float* __restrict__ norm_sq, unsigned int* __restrict__ cand)
{
    __shared__ __attribute__((aligned(128))) char smem[49152];
    const int f  = blockIdx.z;
    const int t0 = blockIdx.y * 256;  // token base within codebook
    const int m0 = blockIdx.x * 128;  // proto base within codebook
    const int tid  = threadIdx.x;
    const int wave = tid >> 6, lane = tid & 63;
    const int wm = wave & 3, wn = wave >> 2;  // wm 0..3 (M), wn 0..1 (N)

    f32x4 acc[4][4] = {};

    // stage one k-half (32 k-elems) of step t into half-buffer h:
    // A 16 chunks (2/wave) + B 8 chunks (1/wave); 3 global_load_lds per wave
    auto stage = [&](int t, int h) {
        int qb = t * 8 + h * 4;
        char* base = smem + h * 24576;
        #pragma unroll
        for (int i = 0; i < 2; ++i) {
            int Rl = wave * 2 + i;
            const short* g = zh + (((size_t)f * 256 + (t0 >> 4) + Rl) * 64 + qb) * 128
                           + (size_t)lane * 8;
            __builtin_amdgcn_global_load_lds(
                (const __attribute__((address_space(1))) void*)g,
                (__attribute__((address_space(3))) void*)(base + Rl * 1024), 16, 0, 0);
        }
        const short* g = eh + (((size_t)f * 256 + (m0 >> 4) + wave) * 64 + qb) * 128
                       + (size_t)lane * 8;
        __builtin_amdgcn_global_load_lds(
            (const __attribute__((address_space(1))) void*)g,
            (__attribute__((address_space(3))) void*)(base + 16384 + wave * 1024), 16, 0, 0);
    };

    stage(0, 0);
    stage(0, 1);
    __syncthreads();

    for (int t = 0; t < 8; ++t) {
        #pragma unroll
        for (int h = 0; h < 2; ++h) {
            const char* base = smem + h * 24576;
            bf16x8 af[4], bfr[4];
            #pragma unroll
            for (int mi = 0; mi < 4; ++mi)
                af[mi] = *(const bf16x8*)(base + (wm * 4 + mi) * 1024 + lane * 16);
            #pragma unroll
            for (int nj = 0; nj < 4; ++nj)
                bfr[nj] = *(const bf16x8*)(base + 16384 + (wn * 4 + nj) * 1024 + lane * 16);
            __syncthreads();              // all waves' kh_h(t) reads done; 1-phase-old stages drained
            if (t < 7) stage(t + 1, h);   // overwrite kh_h in place for step t+1
            #pragma unroll
            for (int mi = 0; mi < 4; ++mi)
                #pragma unroll
                for (int nj = 0; nj < 4; ++nj)
                    acc[mi][nj] = __builtin_amdgcn_mfma_f32_16x16x32_bf16(af[mi], bfr[nj], acc[mi][nj], 0, 0, 0);
        }
    }

    // ---- selection epilogue: per token, top-2 over this wave's 64 cols ----
    // C/D layout (16x16x32): col = lane&15, row = (lane>>4)*4 + reg
    // u32 pack: score high bits | (col_local ^ 63)  (tie -> lower col wins;
    // truncation error <= 2e-4 absorbed by MARGIN; exact rescore follows)
    float inm[4]; unsigned ccode[4];
    #pragma unroll
    for (int nj = 0; nj < 4; ++nj) {
        int col = nj * 16 + (lane & 15);              // [0,64) within wave group
        ccode[nj] = (unsigned)(col ^ 63);
        inm[nj] = rsqrtf(norm_sq[f * NE + m0 + wn * 64 + col]);
    }

    #pragma unroll
    for (int mi = 0; mi < 4; ++mi) {
        #pragma unroll
        for (int r = 0; r < 4; ++r) {
            unsigned p1 = 0u, p2 = 0u;
            #pragma unroll
            for (int nj = 0; nj < 4; ++nj) {
                float w = acc[mi][nj][r] * inm[nj];
                unsigned pw = (ford(w) & 0xFFFFFFC0u) | ccode[nj];
                if (pw > p1) { p2 = p1; p1 = pw; }
                else if (pw > p2) p2 = pw;
            }
            // merge top-2 across the 16 contiguous lanes of this token row
            #pragma unroll
            for (int off = 8; off; off >>= 1) {
                unsigned q1 = __shfl_down(p1, off, 16);
                unsigned q2 = __shfl_down(p2, off, 16);
                if (q1 > p1) { unsigned tt = p1; p1 = q1; p2 = (tt > q2) ? tt : q2; }
                else         { p2 = (p2 > q1) ? p2 : q1; }
            }
            if ((lane & 15) == 0) {
                int u = t0 + wm * 64 + mi * 16 + (lane >> 4) * 4 + r;
                int b = u >> 8, n = u & 255;
                int gt = ((b * FCB + f) << 8) + n;   // global token id (b,f,n)
                int s = (blockIdx.x << 1) | wn;      // slot covers cols s*64..
                uint2 val; val.x = p1; val.y = p2;
                *(uint2*)(cand + ((size_t)gt << 7) + (s << 1)) = val;
            }
        }
    }
}

// ---- rescore + output epilogue: one wave per token (exact norms in-kernel);
// ---- per-token loss contribution fused via device-scope atomicAdd ---------
__global__ __launch_bounds__(256) void rescore_epilogue(
    const float* __restrict__ z, const float* __restrict__ emb,
    const unsigned int* __restrict__ cand, float* __restrict__ out)
{
    int t = blockIdx.x * 4 + (threadIdx.x >> 6);   // global token (b,f,n)
    int lane = threadIdx.x & 63;
    int n = t & 255;
    int f = (t >> 8) & 1;
    int b = t >> 9;
    const float* zrow = z + ((size_t)(b*NN + n))*EDIM + f*CC;
    float4 za = *(const float4*)(zrow + lane * 8);
    float4 zb = *(const float4*)(zrow + lane * 8 + 4);

    // 128 candidates: lane reads slot s == lane (2 packed u32)
    uint2 cc = *(const uint2*)(cand + ((size_t)t << 7) + (lane << 1));
    unsigned c1 = cc.x, c2 = cc.y;

    unsigned m1 = (c1 > c2) ? c1 : c2;
    #pragma unroll
    for (int off = 32; off; off >>= 1) {
        unsigned o = __shfl_xor(m1, off);
        if (o > m1) m1 = o;
    }
    float thr = unford(m1) - MARGIN;

    unsigned long long bestp = 0ull;
    #pragma unroll
    for (int rnd = 0; rnd < 2; ++rnd) {
        unsigned u = rnd ? c2 : c1;
        float v = unford(u);
        unsigned long long mask = __ballot(v > thr);
        while (mask) {
            int src = __ffsll((long long)mask) - 1;
            mask &= mask - 1;
            unsigned cu = __shfl(u, src);
            int idx = (src << 6) | ((int)(cu & 63u) ^ 63);   // proto index [0,4096)
            const float* er = emb + ((size_t)(f * NE + idx)) * CC;
            float4 ea = *(const float4*)(er + lane * 8);
            float4 eb = *(const float4*)(er + lane * 8 + 4);
            float d  = za.x*ea.x + za.y*ea.y + za.z*ea.z + za.w*ea.w
                     + zb.x*eb.x + zb.y*eb.y + zb.z*eb.z + zb.w*eb.w;
            float se = ea.x*ea.x + ea.y*ea.y + ea.z*ea.z + ea.w*ea.w
                     + eb.x*eb.x + eb.y*eb.y + eb.z*eb.z + eb.w*eb.w;
            #pragma unroll
            for (int off = 32; off; off >>= 1) {
                d  += __shfl_xor(d, off);
                se += __shfl_xor(se, off);
            }
            float vex = d / fmaxf(sqrtf(se), 1e-12f);        // exact score
            unsigned long long pex = ((unsigned long long)ford(vex) << 32)
                                   | (unsigned int)(~(unsigned int)idx);
            if (pex > bestp) bestp = pex;
        }
    }
    int idxb = (int)(~(unsigned int)bestp);    // exact argmax (tie -> lower idx)

    // ---- output: z_q gather (codebook-0 row, faithful quirk) + loss -------
    const float* er0 = emb + (size_t)idxb * CC;
    float4 ea = *(const float4*)(er0 + lane * 8);
    float4 eb = *(const float4*)(er0 + lane * 8 + 4);
    float se0 = ea.x*ea.x + ea.y*ea.y + ea.z*ea.z + ea.w*ea.w
              + eb.x*eb.x + eb.y*eb.y + eb.z*eb.z + eb.w*eb.w;
    #pragma unroll
    for (int off = 32; off; off >>= 1) se0 += __shfl_xor(se0, off);
    float inm0 = 1.0f / fmaxf(sqrtf(se0), 1e-12f);
    float* orow = out + ((size_t)(b*NN + n))*EDIM + f*CC;
    ea.x *= inm0; ea.y *= inm0; ea.z *= inm0; ea.w *= inm0;
    eb.x *= inm0; eb.y *= inm0; eb.z *= inm0; eb.w *= inm0;
    *(float4*)(orow + lane * 8) = ea;
    *(float4*)(orow + lane * 8 + 4) = eb;
    float s1 = za.x*za.x + za.y*za.y + za.z*za.z + za.w*za.w
             + zb.x*zb.x + zb.y*zb.y + zb.z*zb.z + zb.w*zb.w;
    float s2 = za.x*ea.x + za.y*ea.y + za.z*ea.z + za.w*ea.w
             + zb.x*eb.x + zb.y*eb.y + zb.z*eb.z + zb.w*eb.w;
    #pragma unroll
    for (int off = 32; off; off >>= 1) {
        s1 += __shfl_xor(s1, off);
        s2 += __shfl_xor(s2, off);
    }
    if (lane == 0) {
        float cosv = s2 / fmaxf(sqrtf(s1), 1e-12f);   // zn . z_q
        float loss = 2.0f - 2.0f * cosv;
        atomicAdd(out + OUT_LOSS, loss * (1.25f / (float)OUT_LOSS));
        out[OUT_IDX + t] = (float)idxb;               // indices read back as float
    }
}

extern "C" void kernel_launch(void* const* d_in, const int* in_sizes, int n_in,
                              void* d_out, int out_size, void* d_ws, size_t ws_size,
                              hipStream_t stream) {
    const float* z   = (const float*)d_in[0];
    const float* emb = (const float*)d_in[1];
    float* out = (float*)d_out;

    char* ws = (char*)d_ws;
    float* norm_sq = (float*)ws;                                    // 32 KB
    unsigned int* cand = (unsigned int*)(ws + 32768);               // 4 MB
    short* z_hi = (short*)(ws + 65536 + (size_t)4*1024*1024);       // 8 MB
    short* e_hi = z_hi + (size_t)FCB * NE * CC;                     // 8 MB
    // ws needed: ~20.1 MB

    hipMemsetAsync(norm_sq, 0, ROWS * sizeof(float), stream);
    hipMemsetAsync(out + OUT_LOSS, 0, sizeof(float), stream);
    pack_hi<<<4096, 256, 0, stream>>>(z, emb, z_hi, e_hi, norm_sq);
    gemm_sel<<<dim3(NE/128, 4096/256, FCB), 512, 0, stream>>>(z_hi, e_hi, norm_sq, cand);
    rescore_epilogue<<<TOKENS/4, 256, 0, stream>>>(z, emb, cand, out);
}

// Round 3
// 149.458 us; speedup vs baseline: 1.6210x; 1.6210x over previous
//
#include <hip/hip_runtime.h>
#include <hip/hip_bf16.h>
#include <stdint.h>

// Problem constants (fixed by setup_inputs)
#define FCB 2            // codebooks
#define BB 16            // batch
#define NN 256           // tokens per (b)
#define EDIM 1024
#define CC 512           // channels per codebook
#define NE 4096          // prototypes per codebook
#define TOKENS (BB*FCB*NN)   // 8192
#define ROWS (FCB*NE)        // 8192 emb rows
#define OUT_LOSS (BB*NN*EDIM)   // 4194304 (also the element count for the mean)
#define OUT_IDX  (OUT_LOSS + 1)
#define MARGIN 0.15f     // rescore margin, v-units (v = z.e/||e|| ~ 22.6*cos); ~24 sigma of bf16 noise

typedef __attribute__((ext_vector_type(8))) short bf16x8;   // MFMA A/B frag (4 VGPRs)
typedef __attribute__((ext_vector_type(4))) float f32x4;    // 16x16 MFMA C/D frag

// monotonic float<->uint mapping for packed argmax
__device__ __forceinline__ unsigned int ford(float v) {
    unsigned int u = __float_as_uint(v);
    return (u & 0x80000000u) ? ~u : (u | 0x80000000u);
}
__device__ __forceinline__ float unford(unsigned int u) {
    unsigned int b = (u & 0x80000000u) ? (u & 0x7fffffffu) : ~u;
    return __uint_as_float(b);
}

// ---------------------------------------------------------------------------
// ws layout:
//   [0]        norm_sq   8192 f32                   (32 KB)  memset 0, atomic-accumulated
//   [32768]    cand      8192 tok x 64 slots x 2 u32 (4 MB)  top-2 per 64-col group
//   [32768+4M] loss_tok  8192 f32                   (32 KB)
//   [+32KB]    z_hi      2*4096*512 bf16            (8 MB)   fragment-packed
//   [+8MB]     e_hi      2*4096*512 bf16            (8 MB)
// Packed layout: elem = ((f*256 + R)*64 + Q)*128 + m*8 + j
//   (R = 16-row tile, Q = 8-elem k-chunk, m = row-in-tile, j = elem).
//   One 1-KB staging chunk = (R, qb..qb+3) = 16 rows x 32 k; both the
//   global_load_lds staging and ds_read_b128 fragment reads are lane-linear
//   (lane <-> 16 B), conflict-free.  (R3/R5-proven layout.)
// ---------------------------------------------------------------------------

// ---- pack: fp32 -> bf16 hi, fragment-packed; emb blocks also accumulate ----
// per-row norm^2 partials into norm_sq (selection-only precision).
__global__ __launch_bounds__(256) void pack_hi(
    const float* __restrict__ z, const float* __restrict__ emb,
    short* __restrict__ z_hi, short* __restrict__ e_hi,
    float* __restrict__ norm_sq)
{
    __shared__ float red[256];
    int bid = blockIdx.x;
    int tid = threadIdx.x;
    bool is_emb = (bid >= 2048);
    const float* src; short* hi; int RS, FRO, FCO;
    if (!is_emb) { src = z;   hi = z_hi; RS = EDIM; FRO = 0;  FCO = CC; }
    else         { src = emb; hi = e_hi; RS = CC;   FRO = NE; FCO = 0; bid -= 2048; }
    int u = bid * 256 + tid;                  // [0, 524288)
    int m = u & 15;
    int Q = (u >> 4) & 63;
    int R = (u >> 10) & 255;
    int f = u >> 18;
    int row = R * 16 + m;
    const float* s = src + (size_t)(f * FRO + row) * RS + f * FCO + Q * 8;
    float4 v0 = *(const float4*)s;
    float4 v1 = *(const float4*)(s + 4);
    float vv[8] = {v0.x, v0.y, v0.z, v0.w, v1.x, v1.y, v1.z, v1.w};
    bf16x8 h8;
    float ss = 0.f;
    #pragma unroll
    for (int j = 0; j < 8; ++j) {
        __hip_bfloat16 hb = __float2bfloat16(vv[j]);
        h8[j] = *(short*)&hb;
        ss = fmaf(vv[j], vv[j], ss);
    }
    *(bf16x8*)(hi + (size_t)u * 8) = h8;

    if (is_emb) {
        // block covers 16 rows x 128 k-elems; reduce over the 16 Q-threads/row
        red[tid] = ss;
        __syncthreads();
        if (tid < 16) {
            float t = 0.f;
            #pragma unroll
            for (int q = 0; q < 16; ++q) t += red[tid + 16 * q];
            int bf = (bid * 256) >> 18;
            int bR = ((bid * 256) >> 10) & 255;
            atomicAdd(norm_sq + bf * NE + bR * 16 + tid, t);
        }
    }
}

// ---------------------------------------------------------------------------
// 2-phase double-buffered bf16 MFMA GEMM (128x128, BK=64) + top-2 select.
// 4 waves (2x2), wave = 64x64 = 4x4 tiles of 16x16x32, acc[4][4].
// Per step t: { stage(t+1 -> buf^1); ds_read frags(buf); 32 MFMA; sync; }
// The syncthreads' implicit vmcnt(0) drain sits ~700 cyc AFTER the stage
// issue (covered by ds_read + 32 MFMA), instead of R0's ~0 cyc -- the T3
// "minimum 2-phase" recipe with pure barrier semantics.  Step loop is fully
// unrolled so buffer selection is compile-time (provably disjoint halves; no
// conservative compiler waits).  64 KiB LDS -> 2 blocks/CU for cross-block
// hiding on top of the within-block pipeline.
// ---------------------------------------------------------------------------
__global__ __launch_bounds__(256, 2) void gemm_sel(
    const short* __restrict__ zh, const short* __restrict__ eh,
    const float* __restrict__ norm_sq, unsigned int* __restrict__ cand)
{
    __shared__ __attribute__((aligned(128))) char smem[2][32768];  // [buf][A 16K | B 16K]
    const int f  = blockIdx.z;
    const int t0 = blockIdx.y * 128;  // token base within codebook
    const int m0 = blockIdx.x * 128;  // proto base within codebook
    const int tid  = threadIdx.x;
    const int wave = tid >> 6, lane = tid & 63;
    const int wm = wave & 1, wn = wave >> 1;

    f32x4 acc[4][4] = {};

    // stage one full BK=64 step (32 KB): A chunks 0..15, B chunks 16..31
    auto stage = [&](int step, char* dst) {
        #pragma unroll
        for (int i = 0; i < 8; ++i) {
            int c = wave * 8 + i;
            const short* gsrc = (c < 16) ? zh : eh;
            int cl = c & 15;
            int Rl = cl >> 1, h = cl & 1;
            int R = ((c < 16) ? (t0 >> 4) : (m0 >> 4)) + Rl;
            int qb = step * 8 + h * 4;
            const short* g = gsrc
                + (((size_t)f * 256 + R) * 64 + qb) * 128 + (size_t)lane * 8;
            __builtin_amdgcn_global_load_lds(
                (const __attribute__((address_space(1))) void*)g,
                (__attribute__((address_space(3))) void*)(dst + c * 1024),
                16, 0, 0);
        }
    };

    stage(0, smem[0]);
    __syncthreads();                  // buf0 ready

    #pragma unroll
    for (int step = 0; step < 8; ++step) {
        const char* cur = smem[step & 1];
        if (step < 7) stage(step + 1, smem[(step & 1) ^ 1]);  // prefetch next

        #pragma unroll
        for (int h = 0; h < 2; ++h) {
            bf16x8 ah[4], bh[4];
            #pragma unroll
            for (int i = 0; i < 4; ++i) {
                ah[i] = *(const bf16x8*)(cur + ((wm*4 + i)*2 + h) * 1024 + lane * 16);
                bh[i] = *(const bf16x8*)(cur + 16384 + ((wn*4 + i)*2 + h) * 1024 + lane * 16);
            }
            #pragma unroll
            for (int i = 0; i < 4; ++i)
                #pragma unroll
                for (int j2 = 0; j2 < 4; ++j2)
                    acc[i][j2] = __builtin_amdgcn_mfma_f32_16x16x32_bf16(ah[i], bh[j2], acc[i][j2], 0, 0, 0);
        }
        __syncthreads();              // reads of cur done; next-step stage drained
    }

    // ---- selection epilogue: per token, top-2 over this wave's 64 cols ----
    // C/D layout (16x16x32): col = lane&15, row = (lane>>4)*4 + reg
    // u32 pack: score high bits | (col_local ^ 63)  (tie -> lower col wins;
    // truncation error <= 2e-4 absorbed by MARGIN; exact rescore follows)
    float inm[4]; unsigned ccode[4];
    #pragma unroll
    for (int j2 = 0; j2 < 4; ++j2) {
        int col = j2 * 16 + (lane & 15);              // [0,64) within wave group
        ccode[j2] = (unsigned)(col ^ 63);
        inm[j2] = rsqrtf(norm_sq[f * NE + m0 + wn * 64 + col]);
    }

    #pragma unroll
    for (int i = 0; i < 4; ++i) {
        #pragma unroll
        for (int r = 0; r < 4; ++r) {
            unsigned p1 = 0u, p2 = 0u;
            #pragma unroll
            for (int j2 = 0; j2 < 4; ++j2) {
                float w = acc[i][j2][r] * inm[j2];
                unsigned pw = (ford(w) & 0xFFFFFFC0u) | ccode[j2];
                if (pw > p1) { p2 = p1; p1 = pw; }
                else if (pw > p2) p2 = pw;
            }
            // merge top-2 across the 16 contiguous lanes of this token row
            #pragma unroll
            for (int off = 8; off; off >>= 1) {
                unsigned q1 = __shfl_down(p1, off, 16);
                unsigned q2 = __shfl_down(p2, off, 16);
                if (q1 > p1) { unsigned t = p1; p1 = q1; p2 = (t > q2) ? t : q2; }
                else         { p2 = (p2 > q1) ? p2 : q1; }
            }
            if ((lane & 15) == 0) {
                int u = t0 + wm * 64 + i * 16 + (lane >> 4) * 4 + r;
                int b = u >> 8, n = u & 255;
                int gt = ((b * FCB + f) << 8) + n;   // global token id (b,f,n)
                int s = (blockIdx.x << 1) | wn;      // slot covers cols s*64..
                uint2 val; val.x = p1; val.y = p2;
                *(uint2*)(cand + ((size_t)gt << 7) + (s << 1)) = val;
            }
        }
    }
}

// ---- rescore + output epilogue: one wave per token; exact dot, norms from
// ---- precomputed f32 norm_sq (one uniform scalar load per candidate) ------
__global__ __launch_bounds__(256) void rescore_epilogue(
    const float* __restrict__ z, const float* __restrict__ emb,
    const unsigned int* __restrict__ cand, const float* __restrict__ norm_sq,
    float* __restrict__ out, float* __restrict__ loss_tok)
{
    int t = blockIdx.x * 4 + (threadIdx.x >> 6);   // global token (b,f,n)
    int lane = threadIdx.x & 63;
    int n = t & 255;
    int f = (t >> 8) & 1;
    int b = t >> 9;
    const float* zrow = z + ((size_t)(b*NN + n))*EDIM + f*CC;
    float4 za = *(const float4*)(zrow + lane * 8);
    float4 zb = *(const float4*)(zrow + lane * 8 + 4);

    // 128 candidates: lane reads slot s == lane (2 packed u32)
    uint2 cc = *(const uint2*)(cand + ((size_t)t << 7) + (lane << 1));
    unsigned c1 = cc.x, c2 = cc.y;

    unsigned m1 = (c1 > c2) ? c1 : c2;
    #pragma unroll
    for (int off = 32; off; off >>= 1) {
        unsigned o = __shfl_xor(m1, off);
        if (o > m1) m1 = o;
    }
    float thr = unford(m1) - MARGIN;

    unsigned long long bestp = 0ull;
    #pragma unroll
    for (int rnd = 0; rnd < 2; ++rnd) {
        unsigned u = rnd ? c2 : c1;
        float v = unford(u);
        unsigned long long mask = __ballot(v > thr);
        while (mask) {
            int src = __ffsll((long long)mask) - 1;
            mask &= mask - 1;
            unsigned cu = __shfl(u, src);
            int idx = (src << 6) | ((int)(cu & 63u) ^ 63);   // proto index [0,4096)
            const float* er = emb + ((size_t)(f * NE + idx)) * CC;
            float4 ea = *(const float4*)(er + lane * 8);
            float4 eb = *(const float4*)(er + lane * 8 + 4);
            float d  = za.x*ea.x + za.y*ea.y + za.z*ea.z + za.w*ea.w
                     + zb.x*eb.x + zb.y*eb.y + zb.z*eb.z + zb.w*eb.w;
            #pragma unroll
            for (int off = 32; off; off >>= 1) d += __shfl_xor(d, off);
            float se = norm_sq[f * NE + idx];                // exact f32 row norm^2
            float vex = d / fmaxf(sqrtf(se), 1e-12f);        // exact score
            unsigned long long pex = ((unsigned long long)ford(vex) << 32)
                                   | (unsigned int)(~(unsigned int)idx);
            if (pex > bestp) bestp = pex;
        }
    }
    int idxb = (int)(~(unsigned int)bestp);    // exact argmax (tie -> lower idx)

    // ---- output: z_q gather (codebook-0 row, faithful quirk) + loss -------
    // norm of the gathered GLOBAL row idxb (in [0,4096)) == norm_sq[idxb]
    const float* er0 = emb + (size_t)idxb * CC;
    float4 ea = *(const float4*)(er0 + lane * 8);
    float4 eb = *(const float4*)(er0 + lane * 8 + 4);
    float inm0 = 1.0f / fmaxf(sqrtf(norm_sq[idxb]), 1e-12f);
    float* orow = out + ((size_t)(b*NN + n))*EDIM + f*CC;
    ea.x *= inm0; ea.y *= inm0; ea.z *= inm0; ea.w *= inm0;
    eb.x *= inm0; eb.y *= inm0; eb.z *= inm0; eb.w *= inm0;
    *(float4*)(orow + lane * 8) = ea;
    *(float4*)(orow + lane * 8 + 4) = eb;
    float s1 = za.x*za.x + za.y*za.y + za.z*za.z + za.w*za.w
             + zb.x*zb.x + zb.y*zb.y + zb.z*zb.z + zb.w*zb.w;
    float s2 = za.x*ea.x + za.y*ea.y + za.z*ea.z + za.w*ea.w
             + zb.x*eb.x + zb.y*eb.y + zb.z*eb.z + zb.w*eb.w;
    #pragma unroll
    for (int off = 32; off; off >>= 1) {
        s1 += __shfl_xor(s1, off);
        s2 += __shfl_xor(s2, off);
    }
    if (lane == 0) {
        float cosv = s2 / fmaxf(sqrtf(s1), 1e-12f);   // zn . z_q (z_q already unit)
        loss_tok[t] = 2.0f - 2.0f * cosv;
        out[OUT_IDX + t] = (float)idxb;               // indices read back as float
    }
}

// ---- final: sum per-token losses -> out[OUT_LOSS] --------------------------
__global__ __launch_bounds__(256) void loss_reduce(
    const float* __restrict__ loss_tok, float* __restrict__ out)
{
    int tid = threadIdx.x;
    float s = 0.f;
    #pragma unroll
    for (int h = 0; h < 32; ++h) s += loss_tok[h * 256 + tid];
    #pragma unroll
    for (int off = 32; off; off >>= 1) s += __shfl_down(s, off);
    __shared__ float part[4];
    if ((tid & 63) == 0) part[tid >> 6] = s;
    __syncthreads();
    if (tid == 0) {
        float t = part[0] + part[1] + part[2] + part[3];
        out[OUT_LOSS] = t * (1.25f / (float)OUT_LOSS);
    }
}

extern "C" void kernel_launch(void* const* d_in, const int* in_sizes, int n_in,
                              void* d_out, int out_size, void* d_ws, size_t ws_size,
                              hipStream_t stream) {
    const float* z   = (const float*)d_in[0];
    const float* emb = (const float*)d_in[1];
    float* out = (float*)d_out;

    char* ws = (char*)d_ws;
    float* norm_sq = (float*)ws;                                    // 32 KB
    unsigned int* cand = (unsigned int*)(ws + 32768);               // 4 MB
    float* loss_tok = (float*)(ws + 32768 + (size_t)4*1024*1024);   // 32 KB
    short* z_hi = (short*)(ws + 65536 + (size_t)4*1024*1024);       // 8 MB
    short* e_hi = z_hi + (size_t)FCB * NE * CC;                     // 8 MB
    // ws needed: ~20.1 MB

    hipMemsetAsync(norm_sq, 0, ROWS * sizeof(float), stream);
    pack_hi<<<4096, 256, 0, stream>>>(z, emb, z_hi, e_hi, norm_sq);
    gemm_sel<<<dim3(NE/128, NE/128, FCB), 256, 0, stream>>>(z_hi, e_hi, norm_sq, cand);
    rescore_epilogue<<<TOKENS/4, 256, 0, stream>>>(z, emb, cand, norm_sq, out, loss_tok);
    loss_reduce<<<1, 256, 0, stream>>>(loss_tok, out);
}

// Round 4
// 147.568 us; speedup vs baseline: 1.6417x; 1.0128x over previous
//
#include <hip/hip_runtime.h>
#include <hip/hip_bf16.h>
#include <stdint.h>

// Problem constants (fixed by setup_inputs)
#define FCB 2            // codebooks
#define BB 16            // batch
#define NN 256           // tokens per (b)
#define EDIM 1024
#define CC 512           // channels per codebook
#define NE 4096          // prototypes per codebook
#define TOKENS (BB*FCB*NN)   // 8192
#define ROWS (FCB*NE)        // 8192 emb rows
#define OUT_LOSS (BB*NN*EDIM)   // 4194304 (also the element count for the mean)
#define OUT_IDX  (OUT_LOSS + 1)
#define MARGIN 0.15f     // rescore margin, v-units (v = z.e/||e|| ~ 22.6*cos); ~24 sigma of bf16 noise

typedef __attribute__((ext_vector_type(8))) short bf16x8;   // MFMA A/B frag (4 VGPRs)
typedef __attribute__((ext_vector_type(4))) float f32x4;    // 16x16 MFMA C/D frag

// monotonic float<->uint mapping for packed argmax
__device__ __forceinline__ unsigned int ford(float v) {
    unsigned int u = __float_as_uint(v);
    return (u & 0x80000000u) ? ~u : (u | 0x80000000u);
}
__device__ __forceinline__ float unford(unsigned int u) {
    unsigned int b = (u & 0x80000000u) ? (u & 0x7fffffffu) : ~u;
    return __uint_as_float(b);
}

// ---------------------------------------------------------------------------
// ws layout:
//   [0]        norm_sq   8192 f32                   (32 KB)  written once by pack_hi (no atomics)
//   [32768]    cand      8192 tok x 64 slots x 2 u32 (4 MB)  top-2 per 64-col group
//   [32768+4M] loss_tok  8192 f32                   (32 KB)
//   [+32KB]    z_hi      2*4096*512 bf16            (8 MB)   fragment-packed
//   [+8MB]     e_hi      2*4096*512 bf16            (8 MB)
// Packed layout: elem = ((f*256 + R)*64 + Q)*128 + m*8 + j
//   (R = 16-row tile, Q = 8-elem k-chunk, m = row-in-tile, j = elem).
//   One 1-KB staging chunk = (R, qb..qb+3) = 16 rows x 32 k; both the
//   global_load_lds staging and ds_read_b128 fragment reads are lane-linear
//   (lane <-> 16 B), conflict-free.
// ---------------------------------------------------------------------------

// ---- pack: fp32 -> bf16 hi, fragment-packed.  z half: 2048 blocks, 1 chunk-
// unit per thread.  emb half: 512 blocks, each owns a FULL (f,R) 16-row tile
// (all 512 k) so per-row norm^2 reduces entirely in-block -> plain store,
// no atomics, no memset node.
__global__ __launch_bounds__(256) void pack_hi(
    const float* __restrict__ z, const float* __restrict__ emb,
    short* __restrict__ z_hi, short* __restrict__ e_hi,
    float* __restrict__ norm_sq)
{
    __shared__ float red[256];
    int bid = blockIdx.x;
    int tid = threadIdx.x;
    if (bid < 2048) {
        // ---- z: u in [0, 524288) ----
        int u = bid * 256 + tid;
        int m = u & 15;
        int Q = (u >> 4) & 63;
        int R = (u >> 10) & 255;
        int f = u >> 18;
        int row = R * 16 + m;                       // token row b*256+n
        const float* s = z + (size_t)row * EDIM + f * CC + Q * 8;
        float4 v0 = *(const float4*)s;
        float4 v1 = *(const float4*)(s + 4);
        float vv[8] = {v0.x, v0.y, v0.z, v0.w, v1.x, v1.y, v1.z, v1.w};
        bf16x8 h8;
        #pragma unroll
        for (int j = 0; j < 8; ++j) {
            __hip_bfloat16 hb = __float2bfloat16(vv[j]);
            h8[j] = *(short*)&hb;
        }
        *(bf16x8*)(z_hi + (size_t)u * 8) = h8;
    } else {
        // ---- emb: block owns (f, R): 16 rows x 512 k; 4 chunk-units/thread
        int e = bid - 2048;                         // [0,512)
        int f = e >> 8, R = e & 255;
        int m = tid & 15;                           // same row for all 4 units
        float ss = 0.f;
        #pragma unroll
        for (int i = 0; i < 4; ++i) {
            int ul = tid + 256 * i;                 // [0,1024)
            int Q = (ul >> 4) & 63;
            const float* s = emb + ((size_t)(f * NE + R * 16 + m)) * CC + Q * 8;
            float4 v0 = *(const float4*)s;
            float4 v1 = *(const float4*)(s + 4);
            float vv[8] = {v0.x, v0.y, v0.z, v0.w, v1.x, v1.y, v1.z, v1.w};
            bf16x8 h8;
            #pragma unroll
            for (int j = 0; j < 8; ++j) {
                __hip_bfloat16 hb = __float2bfloat16(vv[j]);
                h8[j] = *(short*)&hb;
                ss = fmaf(vv[j], vv[j], ss);
            }
            int u = ((f * 256 + R) * 64 + Q) * 16 + m;
            *(bf16x8*)(e_hi + (size_t)u * 8) = h8;
        }
        red[tid] = ss;
        __syncthreads();
        if (tid < 16) {
            float t = 0.f;
            #pragma unroll
            for (int q = 0; q < 16; ++q) t += red[tid + 16 * q];
            norm_sq[f * NE + R * 16 + tid] = t;     // exact f32, no atomic
        }
    }
}

// ---------------------------------------------------------------------------
// R0-proven 1-product bf16 MFMA GEMM (128x128, BK=64) + top-2 select, with
// XCD-aware work remap (T1).  HW assigns linear wg round-robin to the 8 XCDs;
// we decode (xcd = wg&7, local = wg>>3) and give each XCD a contiguous
// m0-stripe (4 m0-tiles x 2 f = 1 MB of B bf16, L2-resident) with t0 varying
// fastest among co-resident blocks -> 32 consecutive blocks share the SAME
// 128 KB B-tile and stream the 4 MB A-panel through L2, instead of every
// stage missing to the Infinity Cache (the measured 26%-MfmaUtil wall was
// ~475 MB of L3 staging traffic at ~12 TB/s).
// ---------------------------------------------------------------------------
__global__ __launch_bounds__(256, 3) void gemm_sel(
    const short* __restrict__ zh, const short* __restrict__ eh,
    const float* __restrict__ norm_sq, unsigned int* __restrict__ cand)
{
    __shared__ char smem[32768];      // A 16K | B 16K (tile-major, [tile][h][1KB])
    const int wg  = blockIdx.x + 32 * (blockIdx.y + 32 * blockIdx.z);  // 0..2047
    const int xcd   = wg & 7;
    const int local = wg >> 3;        // 0..255
    const int t0i = local & 31;       // fastest -> co-resident blocks share B
    const int f   = (local >> 5) & 1;
    const int m0i = (xcd << 2) | (local >> 6);   // 0..31, contiguous per XCD
    const int t0 = t0i * 128;         // token base within codebook
    const int m0 = m0i * 128;         // proto base within codebook
    const int tid  = threadIdx.x;
    const int wave = tid >> 6, lane = tid & 63;
    const int wm = wave & 1, wn = wave >> 1;

    f32x4 acc[4][4] = {};

    for (int step = 0; step < 8; ++step) {
        __syncthreads();              // previous compute done before overwrite
        // 32 chunks of 1 KB per step: A (c<16), B (c>=16); wave stages 8
        #pragma unroll
        for (int i = 0; i < 8; ++i) {
            int c = wave * 8 + i;
            const short* gsrc = (c < 16) ? zh : eh;
            int cl = c & 15;
            int Rl = cl >> 1, h = cl & 1;
            int R = ((c < 16) ? (t0 >> 4) : (m0 >> 4)) + Rl;
            int qb = step * 8 + h * 4;
            const short* g = gsrc
                + (((size_t)f * 256 + R) * 64 + qb) * 128 + (size_t)lane * 8;
            __builtin_amdgcn_global_load_lds(
                (const __attribute__((address_space(1))) void*)g,
                (__attribute__((address_space(3))) void*)(smem + c * 1024),
                16, 0, 0);
        }
        __syncthreads();              // staged data visible to all waves

        #pragma unroll
        for (int h = 0; h < 2; ++h) {
            bf16x8 ah[4], bh[4];
            #pragma unroll
            for (int i = 0; i < 4; ++i) {
                ah[i] = *(const bf16x8*)(smem + ((wm*4 + i)*2 + h) * 1024 + lane * 16);
                bh[i] = *(const bf16x8*)(smem + 16384 + ((wn*4 + i)*2 + h) * 1024 + lane * 16);
            }
            #pragma unroll
            for (int i = 0; i < 4; ++i)
                #pragma unroll
                for (int j2 = 0; j2 < 4; ++j2)
                    acc[i][j2] = __builtin_amdgcn_mfma_f32_16x16x32_bf16(ah[i], bh[j2], acc[i][j2], 0, 0, 0);
        }
    }

    // ---- selection epilogue: per token, top-2 over this wave's 64 cols ----
    // C/D layout (16x16x32): col = lane&15, row = (lane>>4)*4 + reg
    // u32 pack: score high bits | (col_local ^ 63)  (tie -> lower col wins;
    // truncation error <= 2e-4 absorbed by MARGIN; exact rescore follows)
    float inm[4]; unsigned ccode[4];
    #pragma unroll
    for (int j2 = 0; j2 < 4; ++j2) {
        int col = j2 * 16 + (lane & 15);              // [0,64) within wave group
        ccode[j2] = (unsigned)(col ^ 63);
        inm[j2] = rsqrtf(norm_sq[f * NE + m0 + wn * 64 + col]);
    }

    #pragma unroll
    for (int i = 0; i < 4; ++i) {
        #pragma unroll
        for (int r = 0; r < 4; ++r) {
            unsigned p1 = 0u, p2 = 0u;
            #pragma unroll
            for (int j2 = 0; j2 < 4; ++j2) {
                float w = acc[i][j2][r] * inm[j2];
                unsigned pw = (ford(w) & 0xFFFFFFC0u) | ccode[j2];
                if (pw > p1) { p2 = p1; p1 = pw; }
                else if (pw > p2) p2 = pw;
            }
            // merge top-2 across the 16 contiguous lanes of this token row
            #pragma unroll
            for (int off = 8; off; off >>= 1) {
                unsigned q1 = __shfl_down(p1, off, 16);
                unsigned q2 = __shfl_down(p2, off, 16);
                if (q1 > p1) { unsigned t = p1; p1 = q1; p2 = (t > q2) ? t : q2; }
                else         { p2 = (p2 > q1) ? p2 : q1; }
            }
            if ((lane & 15) == 0) {
                int u = t0 + wm * 64 + i * 16 + (lane >> 4) * 4 + r;
                int b = u >> 8, n = u & 255;
                int gt = ((b * FCB + f) << 8) + n;   // global token id (b,f,n)
                int s = (m0i << 1) | wn;             // slot covers cols s*64..
                uint2 val; val.x = p1; val.y = p2;
                *(uint2*)(cand + ((size_t)gt << 7) + (s << 1)) = val;
            }
        }
    }
}

// ---- rescore + output epilogue: one wave per token; exact dot, norms from
// ---- precomputed f32 norm_sq (one uniform scalar load per candidate) ------
__global__ __launch_bounds__(256) void rescore_epilogue(
    const float* __restrict__ z, const float* __restrict__ emb,
    const unsigned int* __restrict__ cand, const float* __restrict__ norm_sq,
    float* __restrict__ out, float* __restrict__ loss_tok)
{
    int t = blockIdx.x * 4 + (threadIdx.x >> 6);   // global token (b,f,n)
    int lane = threadIdx.x & 63;
    int n = t & 255;
    int f = (t >> 8) & 1;
    int b = t >> 9;
    const float* zrow = z + ((size_t)(b*NN + n))*EDIM + f*CC;
    float4 za = *(const float4*)(zrow + lane * 8);
    float4 zb = *(const float4*)(zrow + lane * 8 + 4);

    // 128 candidates: lane reads slot s == lane (2 packed u32)
    uint2 cc = *(const uint2*)(cand + ((size_t)t << 7) + (lane << 1));
    unsigned c1 = cc.x, c2 = cc.y;

    unsigned m1 = (c1 > c2) ? c1 : c2;
    #pragma unroll
    for (int off = 32; off; off >>= 1) {
        unsigned o = __shfl_xor(m1, off);
        if (o > m1) m1 = o;
    }
    float thr = unford(m1) - MARGIN;

    unsigned long long bestp = 0ull;
    #pragma unroll
    for (int rnd = 0; rnd < 2; ++rnd) {
        unsigned u = rnd ? c2 : c1;
        float v = unford(u);
        unsigned long long mask = __ballot(v > thr);
        while (mask) {
            int src = __ffsll((long long)mask) - 1;
            mask &= mask - 1;
            unsigned cu = __shfl(u, src);
            int idx = (src << 6) | ((int)(cu & 63u) ^ 63);   // proto index [0,4096)
            const float* er = emb + ((size_t)(f * NE + idx)) * CC;
            float4 ea = *(const float4*)(er + lane * 8);
            float4 eb = *(const float4*)(er + lane * 8 + 4);
            float d  = za.x*ea.x + za.y*ea.y + za.z*ea.z + za.w*ea.w
                     + zb.x*eb.x + zb.y*eb.y + zb.z*eb.z + zb.w*eb.w;
            #pragma unroll
            for (int off = 32; off; off >>= 1) d += __shfl_xor(d, off);
            float se = norm_sq[f * NE + idx];                // exact f32 row norm^2
            float vex = d / fmaxf(sqrtf(se), 1e-12f);        // exact score
            unsigned long long pex = ((unsigned long long)ford(vex) << 32)
                                   | (unsigned int)(~(unsigned int)idx);
            if (pex > bestp) bestp = pex;
        }
    }
    int idxb = (int)(~(unsigned int)bestp);    // exact argmax (tie -> lower idx)

    // ---- output: z_q gather (codebook-0 row, faithful quirk) + loss -------
    // norm of the gathered GLOBAL row idxb (in [0,4096)) == norm_sq[idxb]
    const float* er0 = emb + (size_t)idxb * CC;
    float4 ea = *(const float4*)(er0 + lane * 8);
    float4 eb = *(const float4*)(er0 + lane * 8 + 4);
    float inm0 = 1.0f / fmaxf(sqrtf(norm_sq[idxb]), 1e-12f);
    float* orow = out + ((size_t)(b*NN + n))*EDIM + f*CC;
    ea.x *= inm0; ea.y *= inm0; ea.z *= inm0; ea.w *= inm0;
    eb.x *= inm0; eb.y *= inm0; eb.z *= inm0; eb.w *= inm0;
    *(float4*)(orow + lane * 8) = ea;
    *(float4*)(orow + lane * 8 + 4) = eb;
    float s1 = za.x*za.x + za.y*za.y + za.z*za.z + za.w*za.w
             + zb.x*zb.x + zb.y*zb.y + zb.z*zb.z + zb.w*zb.w;
    float s2 = za.x*ea.x + za.y*ea.y + za.z*ea.z + za.w*ea.w
             + zb.x*eb.x + zb.y*eb.y + zb.z*eb.z + zb.w*eb.w;
    #pragma unroll
    for (int off = 32; off; off >>= 1) {
        s1 += __shfl_xor(s1, off);
        s2 += __shfl_xor(s2, off);
    }
    if (lane == 0) {
        float cosv = s2 / fmaxf(sqrtf(s1), 1e-12f);   // zn . z_q (z_q already unit)
        loss_tok[t] = 2.0f - 2.0f * cosv;
        out[OUT_IDX + t] = (float)idxb;               // indices read back as float
    }
}

// ---- final: sum per-token losses -> out[OUT_LOSS] --------------------------
__global__ __launch_bounds__(256) void loss_reduce(
    const float* __restrict__ loss_tok, float* __restrict__ out)
{
    int tid = threadIdx.x;
    float s = 0.f;
    #pragma unroll
    for (int h = 0; h < 32; ++h) s += loss_tok[h * 256 + tid];
    #pragma unroll
    for (int off = 32; off; off >>= 1) s += __shfl_down(s, off);
    __shared__ float part[4];
    if ((tid & 63) == 0) part[tid >> 6] = s;
    __syncthreads();
    if (tid == 0) {
        float t = part[0] + part[1] + part[2] + part[3];
        out[OUT_LOSS] = t * (1.25f / (float)OUT_LOSS);
    }
}

extern "C" void kernel_launch(void* const* d_in, const int* in_sizes, int n_in,
                              void* d_out, int out_size, void* d_ws, size_t ws_size,
                              hipStream_t stream) {
    const float* z   = (const float*)d_in[0];
    const float* emb = (const float*)d_in[1];
    float* out = (float*)d_out;

    char* ws = (char*)d_ws;
    float* norm_sq = (float*)ws;                                    // 32 KB
    unsigned int* cand = (unsigned int*)(ws + 32768);               // 4 MB
    float* loss_tok = (float*)(ws + 32768 + (size_t)4*1024*1024);   // 32 KB
    short* z_hi = (short*)(ws + 65536 + (size_t)4*1024*1024);       // 8 MB
    short* e_hi = z_hi + (size_t)FCB * NE * CC;                     // 8 MB
    // ws needed: ~20.1 MB

    pack_hi<<<2560, 256, 0, stream>>>(z, emb, z_hi, e_hi, norm_sq);
    gemm_sel<<<dim3(32, 32, FCB), 256, 0, stream>>>(z_hi, e_hi, norm_sq, cand);
    rescore_epilogue<<<TOKENS/4, 256, 0, stream>>>(z, emb, cand, norm_sq, out, loss_tok);
    loss_reduce<<<1, 256, 0, stream>>>(loss_tok, out);
}

// Round 5
// 145.370 us; speedup vs baseline: 1.6666x; 1.0151x over previous
//
#include <hip/hip_runtime.h>
#include <hip/hip_bf16.h>
#include <stdint.h>

// Problem constants (fixed by setup_inputs)
#define FCB 2            // codebooks
#define BB 16            // batch
#define NN 256           // tokens per (b)
#define EDIM 1024
#define CC 512           // channels per codebook
#define NE 4096          // prototypes per codebook
#define TOKENS (BB*FCB*NN)   // 8192
#define ROWS (FCB*NE)        // 8192 emb rows
#define OUT_LOSS (BB*NN*EDIM)   // 4194304 (also the element count for the mean)
#define OUT_IDX  (OUT_LOSS + 1)
#define MARGIN 0.15f     // rescore margin, v-units (v = z.e/||e|| ~ 22.6*cos); ~24 sigma of bf16 noise

typedef __attribute__((ext_vector_type(8))) short bf16x8;   // MFMA A/B frag (4 VGPRs)
typedef __attribute__((ext_vector_type(4))) float f32x4;    // 16x16 MFMA C/D frag

// monotonic float<->uint mapping for packed argmax
__device__ __forceinline__ unsigned int ford(float v) {
    unsigned int u = __float_as_uint(v);
    return (u & 0x80000000u) ? ~u : (u | 0x80000000u);
}
__device__ __forceinline__ float unford(unsigned int u) {
    unsigned int b = (u & 0x80000000u) ? (u & 0x7fffffffu) : ~u;
    return __uint_as_float(b);
}

// ---------------------------------------------------------------------------
// ws layout:
//   [0]        norm_sq   8192 f32                   (32 KB)  written once by pack_hi (no atomics)
//   [32768]    cand      8192 tok x 64 slots x 2 u32 (4 MB)  top-2 per 64-col group
//   [32768+4M] loss_tok  8192 f32                   (32 KB)
//   [+32KB]    z_hi      2*4096*512 bf16            (8 MB)   fragment-packed
//   [+8MB]     e_hi      2*4096*512 bf16            (8 MB)
// Packed layout: elem = ((f*256 + R)*64 + Q)*128 + m*8 + j
//   (R = 16-row tile, Q = 8-elem k-chunk, m = row-in-tile, j = elem).
//   One 1-KB staging chunk = (R, qb..qb+3) = 16 rows x 32 k; both the
//   global_load_lds staging and ds_read_b128 fragment reads are lane-linear
//   (lane <-> 16 B), conflict-free.
// ---------------------------------------------------------------------------

// ---- pack: fp32 -> bf16 hi, fragment-packed.
// z half (blocks 0..511): 8 token rows each, via LDS transpose so BOTH the
//   fp32 reads (contiguous rows) and the packed bf16 stores (lane-linear)
//   are coalesced.  (Old path read 32 B per lane at 4 KB inter-lane stride.)
// emb half (blocks 512..1023): block owns a full (f,R) 16-row tile (all 512 k)
//   so per-row norm^2 reduces entirely in-block -> plain f32 store, no atomics.
__global__ __launch_bounds__(256) void pack_hi(
    const float* __restrict__ z, const float* __restrict__ emb,
    short* __restrict__ z_hi, short* __restrict__ e_hi,
    float* __restrict__ norm_sq)
{
    int bid = blockIdx.x;
    int tid = threadIdx.x;
    if (bid < 512) {
        // ---- z: 8 rows x 1024 cols, LDS-transposed ----
        __shared__ short lds[8][1032];              // +8 pad: <=2-way banks
        int row0 = bid * 8;                         // token row base
        #pragma unroll
        for (int it = 0; it < 8; ++it) {
            int flat = it * 256 + tid;              // [0,2048) float4 units
            int row = flat >> 8;                    // 256 float4 per row
            int col4 = flat & 255;
            float4 v = *(const float4*)(z + ((size_t)(row0 + row)) * EDIM + col4 * 4);
            short s0, s1, s2, s3;
            { __hip_bfloat16 h = __float2bfloat16(v.x); s0 = *(short*)&h; }
            { __hip_bfloat16 h = __float2bfloat16(v.y); s1 = *(short*)&h; }
            { __hip_bfloat16 h = __float2bfloat16(v.z); s2 = *(short*)&h; }
            { __hip_bfloat16 h = __float2bfloat16(v.w); s3 = *(short*)&h; }
            short* d = &lds[row][col4 * 4];
            d[0] = s0; d[1] = s1; d[2] = s2; d[3] = s3;
        }
        __syncthreads();
        int R = bid >> 1, mb = (bid & 1) * 8;       // 16-row group, m base
        #pragma unroll
        for (int f = 0; f < 2; ++f) {
            #pragma unroll
            for (int it = 0; it < 2; ++it) {
                int unit = it * 256 + tid;          // [0,512)
                int ml = unit & 7;
                int Q  = unit >> 3;                 // [0,64)
                bf16x8 h8 = *(const bf16x8*)&lds[ml][f * 512 + Q * 8];
                size_t u = ((size_t)((f * 256 + R) * 64 + Q)) * 16 + mb + ml;
                *(bf16x8*)(z_hi + u * 8) = h8;      // lane-linear 16 B stores
            }
        }
    } else {
        // ---- emb: block owns (f, R): 16 rows x 512 k; 4 chunk-units/thread
        __shared__ float red[256];
        int e = bid - 512;                          // [0,512)
        int f = e >> 8, R = e & 255;
        int m = tid & 15;                           // same row for all 4 units
        float ss = 0.f;
        #pragma unroll
        for (int i = 0; i < 4; ++i) {
            int ul = tid + 256 * i;                 // [0,1024)
            int Q = (ul >> 4) & 63;
            const float* s = emb + ((size_t)(f * NE + R * 16 + m)) * CC + Q * 8;
            float4 v0 = *(const float4*)s;
            float4 v1 = *(const float4*)(s + 4);
            float vv[8] = {v0.x, v0.y, v0.z, v0.w, v1.x, v1.y, v1.z, v1.w};
            bf16x8 h8;
            #pragma unroll
            for (int j = 0; j < 8; ++j) {
                __hip_bfloat16 hb = __float2bfloat16(vv[j]);
                h8[j] = *(short*)&hb;
                ss = fmaf(vv[j], vv[j], ss);
            }
            int u = ((f * 256 + R) * 64 + Q) * 16 + m;
            *(bf16x8*)(e_hi + (size_t)u * 8) = h8;
        }
        red[tid] = ss;
        __syncthreads();
        if (tid < 16) {
            float t = 0.f;
            #pragma unroll
            for (int q = 0; q < 16; ++q) t += red[tid + 16 * q];
            norm_sq[f * NE + R * 16 + tid] = t;     // exact f32, no atomic
        }
    }
}

// ---------------------------------------------------------------------------
// R0-proven 1-product bf16 MFMA GEMM (128x128, BK=64) + top-2 select.
// Linear grid mapping (R0; R4's XCD remap tripled FETCH for no gain).
// Staging addresses hoisted: 8 persistent per-chunk pointers advanced by a
// constant stride per K-step (kills the per-step 64-bit address recompute
// that dominated VALUBusy=40%).  ds_read/MFMA/epilogue byte-identical to R0.
// ---------------------------------------------------------------------------
__global__ __launch_bounds__(256, 3) void gemm_sel(
    const short* __restrict__ zh, const short* __restrict__ eh,
    const float* __restrict__ norm_sq, unsigned int* __restrict__ cand)
{
    __shared__ char smem[32768];      // A 16K | B 16K (tile-major, [tile][h][1KB])
    const int f  = blockIdx.z;
    const int t0 = blockIdx.y * 128;  // token base within codebook
    const int m0 = blockIdx.x * 128;  // proto base within codebook
    const int tid  = threadIdx.x;
    const int wave = tid >> 6, lane = tid & 63;
    const int wm = wave & 1, wn = wave >> 1;

    f32x4 acc[4][4] = {};

    // per-chunk staging pointers (step 0), advanced by 1024 shorts per step
    const short* gptr[8];
    #pragma unroll
    for (int i = 0; i < 8; ++i) {
        int c = wave * 8 + i;
        const short* gsrc = (c < 16) ? zh : eh;
        int cl = c & 15;
        int Rl = cl >> 1, h = cl & 1;
        int R = ((c < 16) ? (t0 >> 4) : (m0 >> 4)) + Rl;
        gptr[i] = gsrc + (((size_t)f * 256 + R) * 64 + h * 4) * 128 + (size_t)lane * 8;
    }

    for (int step = 0; step < 8; ++step) {
        __syncthreads();              // previous compute done before overwrite
        // 32 chunks of 1 KB per step: A (c<16), B (c>=16); wave stages 8
        #pragma unroll
        for (int i = 0; i < 8; ++i) {
            __builtin_amdgcn_global_load_lds(
                (const __attribute__((address_space(1))) void*)gptr[i],
                (__attribute__((address_space(3))) void*)(smem + (wave * 8 + i) * 1024),
                16, 0, 0);
            gptr[i] += 1024;          // next K-step (8 Q-chunks * 128 shorts)
        }
        __syncthreads();              // staged data visible to all waves

        #pragma unroll
        for (int h = 0; h < 2; ++h) {
            bf16x8 ah[4], bh[4];
            #pragma unroll
            for (int i = 0; i < 4; ++i) {
                ah[i] = *(const bf16x8*)(smem + ((wm*4 + i)*2 + h) * 1024 + lane * 16);
                bh[i] = *(const bf16x8*)(smem + 16384 + ((wn*4 + i)*2 + h) * 1024 + lane * 16);
            }
            #pragma unroll
            for (int i = 0; i < 4; ++i)
                #pragma unroll
                for (int j2 = 0; j2 < 4; ++j2)
                    acc[i][j2] = __builtin_amdgcn_mfma_f32_16x16x32_bf16(ah[i], bh[j2], acc[i][j2], 0, 0, 0);
        }
    }

    // ---- selection epilogue: per token, top-2 over this wave's 64 cols ----
    // C/D layout (16x16x32): col = lane&15, row = (lane>>4)*4 + reg
    // u32 pack: score high bits | (col_local ^ 63)  (tie -> lower col wins;
    // truncation error <= 2e-4 absorbed by MARGIN; exact rescore follows)
    float inm[4]; unsigned ccode[4];
    #pragma unroll
    for (int j2 = 0; j2 < 4; ++j2) {
        int col = j2 * 16 + (lane & 15);              // [0,64) within wave group
        ccode[j2] = (unsigned)(col ^ 63);
        inm[j2] = rsqrtf(norm_sq[f * NE + m0 + wn * 64 + col]);
    }

    #pragma unroll
    for (int i = 0; i < 4; ++i) {
        #pragma unroll
        for (int r = 0; r < 4; ++r) {
            unsigned p1 = 0u, p2 = 0u;
            #pragma unroll
            for (int j2 = 0; j2 < 4; ++j2) {
                float w = acc[i][j2][r] * inm[j2];
                unsigned pw = (ford(w) & 0xFFFFFFC0u) | ccode[j2];
                if (pw > p1) { p2 = p1; p1 = pw; }
                else if (pw > p2) p2 = pw;
            }
            // merge top-2 across the 16 contiguous lanes of this token row
            #pragma unroll
            for (int off = 8; off; off >>= 1) {
                unsigned q1 = __shfl_down(p1, off, 16);
                unsigned q2 = __shfl_down(p2, off, 16);
                if (q1 > p1) { unsigned t = p1; p1 = q1; p2 = (t > q2) ? t : q2; }
                else         { p2 = (p2 > q1) ? p2 : q1; }
            }
            if ((lane & 15) == 0) {
                int u = t0 + wm * 64 + i * 16 + (lane >> 4) * 4 + r;
                int b = u >> 8, n = u & 255;
                int gt = ((b * FCB + f) << 8) + n;   // global token id (b,f,n)
                int s = (blockIdx.x << 1) | wn;      // slot covers cols s*64..
                uint2 val; val.x = p1; val.y = p2;
                *(uint2*)(cand + ((size_t)gt << 7) + (s << 1)) = val;
            }
        }
    }
}

// ---- rescore + output epilogue: one wave per token; exact dot, norms from
// ---- precomputed f32 norm_sq (one uniform scalar load per candidate) ------
__global__ __launch_bounds__(256) void rescore_epilogue(
    const float* __restrict__ z, const float* __restrict__ emb,
    const unsigned int* __restrict__ cand, const float* __restrict__ norm_sq,
    float* __restrict__ out, float* __restrict__ loss_tok)
{
    int t = blockIdx.x * 4 + (threadIdx.x >> 6);   // global token (b,f,n)
    int lane = threadIdx.x & 63;
    int n = t & 255;
    int f = (t >> 8) & 1;
    int b = t >> 9;
    const float* zrow = z + ((size_t)(b*NN + n))*EDIM + f*CC;
    float4 za = *(const float4*)(zrow + lane * 8);
    float4 zb = *(const float4*)(zrow + lane * 8 + 4);

    // 128 candidates: lane reads slot s == lane (2 packed u32)
    uint2 cc = *(const uint2*)(cand + ((size_t)t << 7) + (lane << 1));
    unsigned c1 = cc.x, c2 = cc.y;

    unsigned m1 = (c1 > c2) ? c1 : c2;
    #pragma unroll
    for (int off = 32; off; off >>= 1) {
        unsigned o = __shfl_xor(m1, off);
        if (o > m1) m1 = o;
    }
    float thr = unford(m1) - MARGIN;

    unsigned long long bestp = 0ull;
    #pragma unroll
    for (int rnd = 0; rnd < 2; ++rnd) {
        unsigned u = rnd ? c2 : c1;
        float v = unford(u);
        unsigned long long mask = __ballot(v > thr);
        while (mask) {
            int src = __ffsll((long long)mask) - 1;
            mask &= mask - 1;
            unsigned cu = __shfl(u, src);
            int idx = (src << 6) | ((int)(cu & 63u) ^ 63);   // proto index [0,4096)
            const float* er = emb + ((size_t)(f * NE + idx)) * CC;
            float4 ea = *(const float4*)(er + lane * 8);
            float4 eb = *(const float4*)(er + lane * 8 + 4);
            float d  = za.x*ea.x + za.y*ea.y + za.z*ea.z + za.w*ea.w
                     + zb.x*eb.x + zb.y*eb.y + zb.z*eb.z + zb.w*eb.w;
            #pragma unroll
            for (int off = 32; off; off >>= 1) d += __shfl_xor(d, off);
            float se = norm_sq[f * NE + idx];                // exact f32 row norm^2
            float vex = d / fmaxf(sqrtf(se), 1e-12f);        // exact score
            unsigned long long pex = ((unsigned long long)ford(vex) << 32)
                                   | (unsigned int)(~(unsigned int)idx);
            if (pex > bestp) bestp = pex;
        }
    }
    int idxb = (int)(~(unsigned int)bestp);    // exact argmax (tie -> lower idx)

    // ---- output: z_q gather (codebook-0 row, faithful quirk) + loss -------
    // norm of the gathered GLOBAL row idxb (in [0,4096)) == norm_sq[idxb]
    const float* er0 = emb + (size_t)idxb * CC;
    float4 ea = *(const float4*)(er0 + lane * 8);
    float4 eb = *(const float4*)(er0 + lane * 8 + 4);
    float inm0 = 1.0f / fmaxf(sqrtf(norm_sq[idxb]), 1e-12f);
    float* orow = out + ((size_t)(b*NN + n))*EDIM + f*CC;
    ea.x *= inm0; ea.y *= inm0; ea.z *= inm0; ea.w *= inm0;
    eb.x *= inm0; eb.y *= inm0; eb.z *= inm0; eb.w *= inm0;
    *(float4*)(orow + lane * 8) = ea;
    *(float4*)(orow + lane * 8 + 4) = eb;
    float s1 = za.x*za.x + za.y*za.y + za.z*za.z + za.w*za.w
             + zb.x*zb.x + zb.y*zb.y + zb.z*zb.z + zb.w*zb.w;
    float s2 = za.x*ea.x + za.y*ea.y + za.z*ea.z + za.w*ea.w
             + zb.x*eb.x + zb.y*eb.y + zb.z*eb.z + zb.w*eb.w;
    #pragma unroll
    for (int off = 32; off; off >>= 1) {
        s1 += __shfl_xor(s1, off);
        s2 += __shfl_xor(s2, off);
    }
    if (lane == 0) {
        float cosv = s2 / fmaxf(sqrtf(s1), 1e-12f);   // zn . z_q (z_q already unit)
        loss_tok[t] = 2.0f - 2.0f * cosv;
        out[OUT_IDX + t] = (float)idxb;               // indices read back as float
    }
}

// ---- final: sum per-token losses -> out[OUT_LOSS] --------------------------
__global__ __launch_bounds__(256) void loss_reduce(
    const float* __restrict__ loss_tok, float* __restrict__ out)
{
    int tid = threadIdx.x;
    float s = 0.f;
    #pragma unroll
    for (int h = 0; h < 32; ++h) s += loss_tok[h * 256 + tid];
    #pragma unroll
    for (int off = 32; off; off >>= 1) s += __shfl_down(s, off);
    __shared__ float part[4];
    if ((tid & 63) == 0) part[tid >> 6] = s;
    __syncthreads();
    if (tid == 0) {
        float t = part[0] + part[1] + part[2] + part[3];
        out[OUT_LOSS] = t * (1.25f / (float)OUT_LOSS);
    }
}

extern "C" void kernel_launch(void* const* d_in, const int* in_sizes, int n_in,
                              void* d_out, int out_size, void* d_ws, size_t ws_size,
                              hipStream_t stream) {
    const float* z   = (const float*)d_in[0];
    const float* emb = (const float*)d_in[1];
    float* out = (float*)d_out;

    char* ws = (char*)d_ws;
    float* norm_sq = (float*)ws;                                    // 32 KB
    unsigned int* cand = (unsigned int*)(ws + 32768);               // 4 MB
    float* loss_tok = (float*)(ws + 32768 + (size_t)4*1024*1024);   // 32 KB
    short* z_hi = (short*)(ws + 65536 + (size_t)4*1024*1024);       // 8 MB
    short* e_hi = z_hi + (size_t)FCB * NE * CC;                     // 8 MB
    // ws needed: ~20.1 MB

    pack_hi<<<1024, 256, 0, stream>>>(z, emb, z_hi, e_hi, norm_sq);
    gemm_sel<<<dim3(NE/128, NE/128, FCB), 256, 0, stream>>>(z_hi, e_hi, norm_sq, cand);
    rescore_epilogue<<<TOKENS/4, 256, 0, stream>>>(z, emb, cand, norm_sq, out, loss_tok);
    loss_reduce<<<1, 256, 0, stream>>>(loss_tok, out);
}